// Round 7
// baseline (116.538 us; speedup 1.0000x reference)
//
#include <hip/hip_runtime.h>
#include <math.h>

#define L_TOT 2304
#define C_TOT 128
// fold 1/ln2 into K so softmax uses native exp2
#define KSCALE 0.36067376022224085f   // 0.25 * log2(e)

#if __has_builtin(__builtin_amdgcn_exp2f)
#define EXP2(x) __builtin_amdgcn_exp2f(x)
#else
#define EXP2(x) __expf(0.69314718055994531f * (x))
#endif

typedef float v4f  __attribute__((ext_vector_type(4)));
typedef __bf16 v8bf __attribute__((ext_vector_type(8)));
typedef __bf16 v4bf __attribute__((ext_vector_type(4)));

#define MFMA_16x16x32_BF16(A, B, C) __builtin_amdgcn_mfma_f32_16x16x32_bf16((A), (B), (C), 0, 0, 0)

// async 16B/lane global->LDS: LDS dest is wave-uniform base + lane*16 (linear!)
__device__ __forceinline__ void async_cp16(const __bf16* g, __bf16* l){
  __builtin_amdgcn_global_load_lds((const __attribute__((address_space(1))) unsigned int*)g,
                                   (__attribute__((address_space(3))) unsigned int*)l,
                                   16, 0, 0);
}

// gfx950 paired-lane swaps
#if __has_builtin(__builtin_amdgcn_permlane32_swap)
__device__ __forceinline__ void pl32swap(unsigned &a, unsigned &b){
  auto r = __builtin_amdgcn_permlane32_swap((int)a, (int)b, false, false);
  a = (unsigned)r[0]; b = (unsigned)r[1];
}
#else
__device__ __forceinline__ void pl32swap(unsigned &a, unsigned &b){
  asm volatile("v_permlane32_swap_b32 %0, %1" : "+v"(a), "+v"(b));
}
#endif
#if __has_builtin(__builtin_amdgcn_permlane16_swap)
__device__ __forceinline__ void pl16swap(unsigned &a, unsigned &b){
  auto r = __builtin_amdgcn_permlane16_swap((int)a, (int)b, false, false);
  a = (unsigned)r[0]; b = (unsigned)r[1];
}
#else
__device__ __forceinline__ void pl16swap(unsigned &a, unsigned &b){
  asm volatile("v_permlane16_swap_b32 %0, %1" : "+v"(a), "+v"(b));
}
#endif

// ================= split-precision MFMA projection =================
// One 128(M) x (NT*16)(N) tile of Y = W @ X + bscale*bias per block.
// MODE 1: Yh[l][m] bf16 transposed, *scale ; 2: Yh[m][l] bf16
template<int MODE, int NT>
__device__ __forceinline__ void mfma_proj(const float* __restrict__ W,
                                          const float* __restrict__ bias,
                                          const float* __restrict__ Xb,
                                          __bf16* __restrict__ Yh,
                                          float scale, float bscale,
                                          int n0, __bf16* Bhi, int tid){
  __bf16* Blo = Bhi + NT * 2176;       // [NT*16][136] each, pad->bank-uniform
  const int wave = tid >> 6, lane = tid & 63, qd = lane >> 4, cn = lane & 15;
  const int m0 = wave * 32;
  v8bf ahi[2][4], alo[2][4];
  #pragma unroll
  for (int rt = 0; rt < 2; rt++)
    #pragma unroll
    for (int ks = 0; ks < 4; ks++){
      const float* wp = W + (size_t)(m0 + rt * 16 + cn) * C_TOT + ks * 32 + qd * 8;
      float4 w0 = *(const float4*)wp;
      float4 w1 = *(const float4*)(wp + 4);
      float wv[8] = {w0.x, w0.y, w0.z, w0.w, w1.x, w1.y, w1.z, w1.w};
      #pragma unroll
      for (int j = 0; j < 8; j++){
        __bf16 h = (__bf16)wv[j];
        ahi[rt][ks][j] = h;
        alo[rt][ks][j] = (__bf16)(wv[j] - (float)h);
      }
    }
  if (NT == 2){
    int k = tid >> 1, nh = tid & 1;
    const float* xp = Xb + (size_t)k * L_TOT + n0 + nh * 16;
    float4 x0 = *(const float4*)xp;
    float4 x1 = *(const float4*)(xp + 4);
    float4 x2 = *(const float4*)(xp + 8);
    float4 x3 = *(const float4*)(xp + 12);
    float xv[16] = {x0.x, x0.y, x0.z, x0.w, x1.x, x1.y, x1.z, x1.w,
                    x2.x, x2.y, x2.z, x2.w, x3.x, x3.y, x3.z, x3.w};
    #pragma unroll
    for (int i = 0; i < 16; i++){
      __bf16 h = (__bf16)xv[i];
      int row = nh * 16 + i;
      Bhi[row * 136 + k] = h;
      Blo[row * 136 + k] = (__bf16)(xv[i] - (float)h);
    }
  } else {
    int k = tid >> 1, half = tid & 1;
    const float* xp = Xb + (size_t)k * L_TOT + n0 + half * 8;
    float4 x0 = *(const float4*)xp;
    float4 x1 = *(const float4*)(xp + 4);
    float xv[8] = {x0.x, x0.y, x0.z, x0.w, x1.x, x1.y, x1.z, x1.w};
    #pragma unroll
    for (int i = 0; i < 8; i++){
      __bf16 h = (__bf16)xv[i];
      int row = half * 8 + i;
      Bhi[row * 136 + k] = h;
      Blo[row * 136 + k] = (__bf16)(xv[i] - (float)h);
    }
  }
  __syncthreads();
  v4f acc[2][NT];
  #pragma unroll
  for (int rt = 0; rt < 2; rt++)
    #pragma unroll
    for (int ct = 0; ct < NT; ct++) acc[rt][ct] = (v4f){0.f, 0.f, 0.f, 0.f};
  #pragma unroll
  for (int ks = 0; ks < 4; ks++){
    v8bf bhi[NT], blo[NT];
    #pragma unroll
    for (int ct = 0; ct < NT; ct++){
      bhi[ct] = *(const v8bf*)&Bhi[(ct * 16 + cn) * 136 + ks * 32 + qd * 8];
      blo[ct] = *(const v8bf*)&Blo[(ct * 16 + cn) * 136 + ks * 32 + qd * 8];
    }
    #pragma unroll
    for (int rt = 0; rt < 2; rt++)
      #pragma unroll
      for (int ct = 0; ct < NT; ct++){
        acc[rt][ct] = MFMA_16x16x32_BF16(ahi[rt][ks], bhi[ct], acc[rt][ct]);
        acc[rt][ct] = MFMA_16x16x32_BF16(ahi[rt][ks], blo[ct], acc[rt][ct]);
        acc[rt][ct] = MFMA_16x16x32_BF16(alo[rt][ks], bhi[ct], acc[rt][ct]);
      }
  }
  #pragma unroll
  for (int rt = 0; rt < 2; rt++){
    float bv[4];
    #pragma unroll
    for (int r = 0; r < 4; r++) bv[r] = bias[m0 + rt * 16 + qd * 4 + r] * bscale;
    #pragma unroll
    for (int ct = 0; ct < NT; ct++){
      int col = n0 + ct * 16 + cn;
      if (MODE == 1){
        v4bf kk;
        #pragma unroll
        for (int r = 0; r < 4; r++) kk[r] = (__bf16)((acc[rt][ct][r] + bv[r]) * scale);
        *(v4bf*)&Yh[(size_t)col * C_TOT + m0 + rt * 16 + qd * 4] = kk;
      } else {
        #pragma unroll
        for (int r = 0; r < 4; r++)
          Yh[(size_t)(m0 + rt * 16 + qd * 4 + r) * L_TOT + col] = (__bf16)(acc[rt][ct][r] + bv[r]);
      }
    }
  }
}

// ================= stage 1: Q projection (16-col tiles) + 2D-DCT of spatial =====
__global__ __launch_bounds__(256) void k_q_dct(
    const float* __restrict__ freq, const float* __restrict__ spat,
    const float* __restrict__ Wq, const float* __restrict__ bq,
    __bf16* __restrict__ QT, float* __restrict__ SF){
  __shared__ __align__(16) unsigned char smraw[34560];
  int tid = threadIdx.x;
  if (blockIdx.x < 288){
    int idx = blockIdx.x;
    int b = idx / 144, n0 = (idx % 144) * 16;
    size_t off = (size_t)b * C_TOT * L_TOT;
    mfma_proj<1, 1>(Wq, bq, freq + off, QT + (size_t)b * L_TOT * C_TOT, 1.0f, 1.0f, n0, (__bf16*)smraw, tid);
    return;
  }
  int img = blockIdx.x - 288;            // 0..255 : b*128 + c
  __bf16* Xhi = (__bf16*)smraw;          // [48][72] each, cols 48..63 zero-padded
  __bf16* Xlo = Xhi + 3456;
  __bf16* Dm  = Xhi + 6912;              // D[a][n]
  __bf16* Thi = Xhi + 10368;             // T^T[w][m]
  __bf16* Tlo = Xhi + 13824;
  const float* src = spat + (size_t)img * 2304;
  for (int i = tid; i < 8640; i += 256) ((unsigned int*)smraw)[i] = 0u;
  __syncthreads();
  for (int i = tid; i < 2304; i += 256){
    int a = i / 48, n = i - a * 48;
    int m = ((2 * n + 1) * a) % 192;      // exact angle reduction, cos period = 192
    float v = cosf(0.032724923474893679f * (float)m) * 0.204124145231931508f;
    if (a == 0) v *= 0.707106781186547524f;
    Dm[a * 72 + n] = (__bf16)v;
  }
  for (int i = tid; i < 2304; i += 256){
    int mm = i / 48, n = i - mm * 48;
    float v = src[i];
    __bf16 h = (__bf16)v;
    Xhi[mm * 72 + n] = h;
    Xlo[mm * 72 + n] = (__bf16)(v - (float)h);
  }
  __syncthreads();
  int wave = tid >> 6, lane = tid & 63, qd = lane >> 4, cn = lane & 15;
  // pass 1: T[m][w] = sum_n X[m][n] D[w][n]
  for (int t = wave; t < 9; t += 4){
    int mi = t / 3, wi = t - mi * 3;
    v8bf ah0 = *(const v8bf*)&Xhi[(mi * 16 + cn) * 72 + qd * 8];
    v8bf ah1 = *(const v8bf*)&Xhi[(mi * 16 + cn) * 72 + 32 + qd * 8];
    v8bf al0 = *(const v8bf*)&Xlo[(mi * 16 + cn) * 72 + qd * 8];
    v8bf al1 = *(const v8bf*)&Xlo[(mi * 16 + cn) * 72 + 32 + qd * 8];
    v8bf b0 = *(const v8bf*)&Dm[(wi * 16 + cn) * 72 + qd * 8];
    v8bf b1 = *(const v8bf*)&Dm[(wi * 16 + cn) * 72 + 32 + qd * 8];
    v4f acc = (v4f){0.f, 0.f, 0.f, 0.f};
    acc = MFMA_16x16x32_BF16(ah0, b0, acc);
    acc = MFMA_16x16x32_BF16(ah1, b1, acc);
    acc = MFMA_16x16x32_BF16(al0, b0, acc);
    acc = MFMA_16x16x32_BF16(al1, b1, acc);
    v4bf th, tl;
    #pragma unroll
    for (int r = 0; r < 4; r++){
      __bf16 h = (__bf16)acc[r];
      th[r] = h;
      tl[r] = (__bf16)(acc[r] - (float)h);
    }
    *(v4bf*)&Thi[(wi * 16 + cn) * 72 + mi * 16 + qd * 4] = th;
    *(v4bf*)&Tlo[(wi * 16 + cn) * 72 + mi * 16 + qd * 4] = tl;
  }
  __syncthreads();
  // pass 2: F[h][w] = sum_m D[h][m] T[m][w]
  float* dst = SF + (size_t)img * 2304;
  for (int t = wave; t < 9; t += 4){
    int hi_ = t / 3, wi = t - hi_ * 3;
    v8bf a0 = *(const v8bf*)&Dm[(hi_ * 16 + cn) * 72 + qd * 8];
    v8bf a1 = *(const v8bf*)&Dm[(hi_ * 16 + cn) * 72 + 32 + qd * 8];
    v8bf bh0 = *(const v8bf*)&Thi[(wi * 16 + cn) * 72 + qd * 8];
    v8bf bh1 = *(const v8bf*)&Thi[(wi * 16 + cn) * 72 + 32 + qd * 8];
    v8bf bl0 = *(const v8bf*)&Tlo[(wi * 16 + cn) * 72 + qd * 8];
    v8bf bl1 = *(const v8bf*)&Tlo[(wi * 16 + cn) * 72 + 32 + qd * 8];
    v4f acc = (v4f){0.f, 0.f, 0.f, 0.f};
    acc = MFMA_16x16x32_BF16(a0, bh0, acc);
    acc = MFMA_16x16x32_BF16(a1, bh1, acc);
    acc = MFMA_16x16x32_BF16(a0, bl0, acc);
    acc = MFMA_16x16x32_BF16(a1, bl1, acc);
    int w = wi * 16 + cn;
    #pragma unroll
    for (int r = 0; r < 4; r++)
      dst[(size_t)(hi_ * 16 + qd * 4 + r) * 48 + w] = acc[r];
  }
}

// ================= stage 2: K,V projections (16-col tiles, 576 blocks) ==========
__global__ __launch_bounds__(256) void k_kv(
    const float* __restrict__ SF,
    const float* __restrict__ Wk, const float* __restrict__ bk,
    const float* __restrict__ Wv, const float* __restrict__ bv,
    __bf16* __restrict__ KT, __bf16* __restrict__ Vg){
  __shared__ __align__(16) unsigned char smraw[8704];
  int job = blockIdx.x / 288;
  int idx = blockIdx.x % 288;
  int b = idx / 144, n0 = (idx % 144) * 16;
  size_t off = (size_t)b * C_TOT * L_TOT;
  if (job == 0)
    mfma_proj<1, 1>(Wk, bk, SF + off, KT + (size_t)b * L_TOT * C_TOT, KSCALE, 1.0f, n0, (__bf16*)smraw, threadIdx.x);
  else
    mfma_proj<2, 1>(Wv, bv, SF + off, Vg + off, 1.0f, 1.0f, n0, (__bf16*)smraw, threadIdx.x);
}

// ================= stage 3: barrier-free MFMA flash attention ====================
// Each wave owns a disjoint 64-key slice per 256-chunk with private K/V LDS
// sub-buffers (double-buffered). Both K and V staged via global_load_lds; V's
// bank swizzle done by pre-swizzling the per-lane GLOBAL source (LDS dest linear).
// Per chunk: issue 4 async for chunk+1 -> s_waitcnt vmcnt(4) (counted, never 0)
// -> sched_barrier -> compute. NO __syncthreads in the loop; waves fully decouple.
__global__ __launch_bounds__(256) void k_attn(const __bf16* __restrict__ QT,
                                              const __bf16* __restrict__ KT,
                                              const __bf16* __restrict__ V,
                                              __bf16* __restrict__ AO){
  const int L = L_TOT;
  int bh = blockIdx.y;
  int b = bh >> 3, h = bh & 7;
  int c0 = h * 16;
  const __bf16* QTb = QT + (size_t)b * L * C_TOT;
  const __bf16* KTb = KT + (size_t)b * L * C_TOT;
  const __bf16* Vb  = V  + ((size_t)b * C_TOT + c0) * L;
  int tid = threadIdx.x;
  int wave = tid >> 6, lane = tid & 63;
  int qd = lane >> 4, cn = lane & 15;
  int l0 = blockIdx.x * 48;

  // per-wave: K 2 x 1024 elems, V 2 x 1024 elems (64 keys x 16 ch each buffer)
  __shared__ __align__(16) __bf16 smem[16384];
  __bf16* KtW = smem + wave * 2048;
  __bf16* VsW = smem + 8192 + wave * 2048;

  v8bf qf[3];
  #pragma unroll
  for (int t = 0; t < 3; t++){
    #pragma unroll
    for (int j = 0; j < 8; j++) qf[t][j] = (__bf16)0.0f;
  }
  if (qd < 2){
    #pragma unroll
    for (int t = 0; t < 3; t++)
      qf[t] = *(const v8bf*)&QTb[(size_t)(l0 + t * 16 + cn) * C_TOT + c0 + qd * 8];
  }

  v4f acc[3];
  float den[3] = {0.f, 0.f, 0.f};
  #pragma unroll
  for (int t = 0; t < 3; t++) acc[t] = (v4f){0.f, 0.f, 0.f, 0.f};

  // K async: lane l covers key j*32+(l>>1), ch half (l&1)*8 -> dest linear j*512+l*8
  // V async: lane l covers ch d=j*8+(l>>3); content at LDS elem d*64+x holds
  //          V[d][x ^ ((d&7)<<3)] (read-side XOR swizzle via pre-swizzled source)
  #define STAGE4(CH, BUF)                                                          \
    {                                                                              \
      int s0w = (CH) * 256 + wave * 64;                                            \
      _Pragma("unroll")                                                            \
      for (int j = 0; j < 2; j++)                                                  \
        async_cp16(KTb + (size_t)(s0w + j * 32 + (lane >> 1)) * C_TOT + c0 +       \
                       (lane & 1) * 8,                                             \
                   KtW + (BUF) * 1024 + j * 512);                                  \
      _Pragma("unroll")                                                            \
      for (int j = 0; j < 2; j++)                                                  \
        async_cp16(Vb + (size_t)(j * 8 + (lane >> 3)) * L + s0w +                  \
                       (((lane & 7) ^ ((lane >> 3) & 7)) << 3),                    \
                   VsW + (BUF) * 1024 + j * 512);                                  \
    }

  STAGE4(0, 0);                       // prologue: chunk 0 -> buffer 0

  for (int ch = 0; ch < 9; ch++){
    int p = ch & 1;
    if (ch < 8){
      STAGE4(ch + 1, p ^ 1);
      asm volatile("s_waitcnt vmcnt(4)" ::: "memory");   // prev chunk's 4 done
    } else {
      asm volatile("s_waitcnt vmcnt(0)" ::: "memory");
    }
    __builtin_amdgcn_sched_barrier(0);                   // no ds_read hoisting

    const __bf16* Kt = KtW + p * 1024;
    const __bf16* Vs = VsW + p * 1024;
    #pragma unroll
    for (int su = 0; su < 2; su++){
      v8bf a0, a1;
      #pragma unroll
      for (int j = 0; j < 8; j++){ a0[j] = (__bf16)0.0f; a1[j] = (__bf16)0.0f; }
      if (qd < 2){
        a0 = *(const v8bf*)&Kt[(su * 32 + cn) * 16 + qd * 8];
        a1 = *(const v8bf*)&Kt[(su * 32 + 16 + cn) * 16 + qd * 8];
      }
      v8bf vf = *(const v8bf*)&Vs[cn * 64 + (((su * 32 + qd * 8)) ^ ((cn & 7) << 3))];
      #pragma unroll
      for (int t = 0; t < 3; t++){
        v4f z = {0.f, 0.f, 0.f, 0.f};
        v4f st0 = MFMA_16x16x32_BF16(a0, qf[t], z);
        v4f st1 = MFMA_16x16x32_BF16(a1, qf[t], z);
        float p0[4], p1[4];
        #pragma unroll
        for (int i = 0; i < 4; i++){
          p0[i] = EXP2(st0[i]); den[t] += p0[i];
          p1[i] = EXP2(st1[i]); den[t] += p1[i];
        }
        v4bf cc0, cc1;
        #pragma unroll
        for (int i = 0; i < 4; i++){ cc0[i] = (__bf16)p0[i]; cc1[i] = (__bf16)p1[i]; }
        unsigned U0 = ((unsigned*)&cc0)[0], U1 = ((unsigned*)&cc0)[1];
        unsigned U2 = ((unsigned*)&cc1)[0], U3 = ((unsigned*)&cc1)[1];
        pl32swap(U0, U2); pl32swap(U1, U3);
        pl16swap(U0, U2); pl16swap(U1, U3);
        v8bf pf;
        ((unsigned*)&pf)[0] = U0; ((unsigned*)&pf)[1] = U1;
        ((unsigned*)&pf)[2] = U2; ((unsigned*)&pf)[3] = U3;
        acc[t] = MFMA_16x16x32_BF16(vf, pf, acc[t]);
      }
    }
  }
  #undef STAGE4

  // cross-wave combine: 12 (wave,tile) slots (single barrier pair)
  __syncthreads();
  float* redA = (float*)smem;            // 3072 floats
  float* redD = (float*)smem + 3072;     // 768 floats
  #pragma unroll
  for (int t = 0; t < 3; t++){
    *(v4f*)&redA[((wave * 3 + t) * 64 + lane) * 4] = acc[t];
    redD[(wave * 3 + t) * 64 + lane] = den[t];
  }
  __syncthreads();
  if (wave < 3){
    int t = wave;
    v4f a = (v4f){0.f, 0.f, 0.f, 0.f};
    float dn = 0.f;
    #pragma unroll
    for (int w2 = 0; w2 < 4; w2++){
      v4f xx = *(const v4f*)&redA[((w2 * 3 + t) * 64 + lane) * 4];
      a[0] += xx[0]; a[1] += xx[1]; a[2] += xx[2]; a[3] += xx[3];
      dn += redD[(w2 * 3 + t) * 64 + lane];
    }
    dn += __shfl_xor(dn, 16);
    dn += __shfl_xor(dn, 32);
    float inv = 1.0f / dn;
    __bf16* Ao = AO + ((size_t)b * C_TOT + c0) * L;
    #pragma unroll
    for (int r2 = 0; r2 < 4; r2++)
      Ao[(size_t)(qd * 4 + r2) * L + l0 + t * 16 + cn] = (__bf16)(a[r2] * inv);
  }
}

// ================= output projection (16-col tiles, 288 blocks) =================
__global__ __launch_bounds__(256) void k_oproj(const __bf16* __restrict__ AO,
                                               const float* __restrict__ Wo, const float* __restrict__ bo,
                                               float* __restrict__ out){
  __shared__ __align__(16) __bf16 Bs[16 * 136];
  int b = blockIdx.y, n0 = blockIdx.x * 16;
  int tid = threadIdx.x;
  const int wave = tid >> 6, lane = tid & 63, qd = lane >> 4, cn = lane & 15;
  const int m0 = wave * 32;
  v8bf ahi[2][4], alo[2][4];
  #pragma unroll
  for (int rt = 0; rt < 2; rt++)
    #pragma unroll
    for (int ks = 0; ks < 4; ks++){
      const float* wp = Wo + (size_t)(m0 + rt * 16 + cn) * C_TOT + ks * 32 + qd * 8;
      float4 w0 = *(const float4*)wp;
      float4 w1 = *(const float4*)(wp + 4);
      float wv[8] = {w0.x, w0.y, w0.z, w0.w, w1.x, w1.y, w1.z, w1.w};
      #pragma unroll
      for (int j = 0; j < 8; j++){
        __bf16 h = (__bf16)wv[j];
        ahi[rt][ks][j] = h;
        alo[rt][ks][j] = (__bf16)(wv[j] - (float)h);
      }
    }
  {
    int k = tid >> 1, half = tid & 1;
    const __bf16* src = AO + ((size_t)b * C_TOT + k) * L_TOT + n0 + half * 8;
    v8bf x0 = *(const v8bf*)src;
    #pragma unroll
    for (int i = 0; i < 8; i++)
      Bs[(half * 8 + i) * 136 + k] = x0[i];
  }
  __syncthreads();
  v4f acc[2];
  #pragma unroll
  for (int rt = 0; rt < 2; rt++) acc[rt] = (v4f){0.f, 0.f, 0.f, 0.f};
  #pragma unroll
  for (int ks = 0; ks < 4; ks++){
    v8bf bf = *(const v8bf*)&Bs[cn * 136 + ks * 32 + qd * 8];
    #pragma unroll
    for (int rt = 0; rt < 2; rt++){
      acc[rt] = MFMA_16x16x32_BF16(ahi[rt][ks], bf, acc[rt]);
      acc[rt] = MFMA_16x16x32_BF16(alo[rt][ks], bf, acc[rt]);
    }
  }
  float* ob = out + (size_t)b * C_TOT * L_TOT;
  #pragma unroll
  for (int rt = 0; rt < 2; rt++){
    float bv[4];
    #pragma unroll
    for (int r = 0; r < 4; r++) bv[r] = bo[m0 + rt * 16 + qd * 4 + r];
    int col = n0 + cn;
    #pragma unroll
    for (int r = 0; r < 4; r++)
      ob[(size_t)(m0 + rt * 16 + qd * 4 + r) * L_TOT + col] = acc[rt][r] + bv[r];
  }
}

extern "C" void kernel_launch(void* const* d_in, const int* in_sizes, int n_in,
                              void* d_out, int out_size, void* d_ws, size_t ws_size,
                              hipStream_t stream){
  const float* freq = (const float*)d_in[0];
  const float* spat = (const float*)d_in[1];
  const float* Wq = (const float*)d_in[2]; const float* bq = (const float*)d_in[3];
  const float* Wk = (const float*)d_in[4]; const float* bk = (const float*)d_in[5];
  const float* Wv = (const float*)d_in[6]; const float* bv = (const float*)d_in[7];
  const float* Wo = (const float*)d_in[8]; const float* bo = (const float*)d_in[9];
  __bf16* base = (__bf16*)d_ws;

  __bf16* QTg = base;                       // [b][l][c]
  __bf16* KTg = base + 589824;              // [b][l][c], +bk, *KSCALE
  __bf16* Vg  = base + 1179648;             // [b][c][l], +bv
  __bf16* AOg = base + 1769472;             // [b][c][l]
  float*  SFg = (float*)(base + 2359296);   // [b][c][l] fp32, DCT'd spatial
  float* out = (float*)d_out;

  k_q_dct<<<dim3(544), dim3(256), 0, stream>>>(freq, spat, Wq, bq, QTg, SFg);
  k_kv<<<dim3(576), dim3(256), 0, stream>>>(SFg, Wk, bk, Wv, bv, KTg, Vg);
  k_attn<<<dim3(48, 16), dim3(256), 0, stream>>>(QTg, KTg, Vg, AOg);
  k_oproj<<<dim3(144, 2), dim3(256), 0, stream>>>(AOg, Wo, bo, out);
}

// Round 8
// 112.957 us; speedup vs baseline: 1.0317x; 1.0317x over previous
//
#include <hip/hip_runtime.h>
#include <math.h>

#define L_TOT 2304
#define C_TOT 128
// fold 1/ln2 into K so softmax uses native exp2
#define KSCALE 0.36067376022224085f   // 0.25 * log2(e)

#if __has_builtin(__builtin_amdgcn_exp2f)
#define EXP2(x) __builtin_amdgcn_exp2f(x)
#else
#define EXP2(x) __expf(0.69314718055994531f * (x))
#endif

typedef float v4f  __attribute__((ext_vector_type(4)));
typedef __bf16 v8bf __attribute__((ext_vector_type(8)));
typedef __bf16 v4bf __attribute__((ext_vector_type(4)));

#define MFMA_16x16x32_BF16(A, B, C) __builtin_amdgcn_mfma_f32_16x16x32_bf16((A), (B), (C), 0, 0, 0)

// async 16B/lane global->LDS: LDS dest is wave-uniform base + lane*16 (linear!)
__device__ __forceinline__ void async_cp16(const __bf16* g, __bf16* l){
  __builtin_amdgcn_global_load_lds((const __attribute__((address_space(1))) unsigned int*)g,
                                   (__attribute__((address_space(3))) unsigned int*)l,
                                   16, 0, 0);
}

// gfx950 paired-lane swaps
#if __has_builtin(__builtin_amdgcn_permlane32_swap)
__device__ __forceinline__ void pl32swap(unsigned &a, unsigned &b){
  auto r = __builtin_amdgcn_permlane32_swap((int)a, (int)b, false, false);
  a = (unsigned)r[0]; b = (unsigned)r[1];
}
#else
__device__ __forceinline__ void pl32swap(unsigned &a, unsigned &b){
  asm volatile("v_permlane32_swap_b32 %0, %1" : "+v"(a), "+v"(b));
}
#endif
#if __has_builtin(__builtin_amdgcn_permlane16_swap)
__device__ __forceinline__ void pl16swap(unsigned &a, unsigned &b){
  auto r = __builtin_amdgcn_permlane16_swap((int)a, (int)b, false, false);
  a = (unsigned)r[0]; b = (unsigned)r[1];
}
#else
__device__ __forceinline__ void pl16swap(unsigned &a, unsigned &b){
  asm volatile("v_permlane16_swap_b32 %0, %1" : "+v"(a), "+v"(b));
}
#endif

// ================= split-precision MFMA projection =================
// One 128(M) x 32(N) tile of Y = W @ X + bscale*bias per block.
// MODE 1: Yh[l][m] bf16 transposed, *scale ; 2: Yh[m][l] bf16
template<int MODE>
__device__ __forceinline__ void mfma_proj(const float* __restrict__ W,
                                          const float* __restrict__ bias,
                                          const float* __restrict__ Xb,
                                          __bf16* __restrict__ Yh,
                                          float scale, float bscale,
                                          int n0, __bf16* Bhi, int tid){
  __bf16* Blo = Bhi + 4352;            // [32][136] each, pad->bank-uniform
  const int wave = tid >> 6, lane = tid & 63, qd = lane >> 4, cn = lane & 15;
  const int m0 = wave * 32;
  v8bf ahi[2][4], alo[2][4];
  #pragma unroll
  for (int rt = 0; rt < 2; rt++)
    #pragma unroll
    for (int ks = 0; ks < 4; ks++){
      const float* wp = W + (size_t)(m0 + rt * 16 + cn) * C_TOT + ks * 32 + qd * 8;
      float4 w0 = *(const float4*)wp;
      float4 w1 = *(const float4*)(wp + 4);
      float wv[8] = {w0.x, w0.y, w0.z, w0.w, w1.x, w1.y, w1.z, w1.w};
      #pragma unroll
      for (int j = 0; j < 8; j++){
        __bf16 h = (__bf16)wv[j];
        ahi[rt][ks][j] = h;
        alo[rt][ks][j] = (__bf16)(wv[j] - (float)h);
      }
    }
  {
    int k = tid >> 1, nh = tid & 1;
    const float* xp = Xb + (size_t)k * L_TOT + n0 + nh * 16;
    float4 x0 = *(const float4*)xp;
    float4 x1 = *(const float4*)(xp + 4);
    float4 x2 = *(const float4*)(xp + 8);
    float4 x3 = *(const float4*)(xp + 12);
    float xv[16] = {x0.x, x0.y, x0.z, x0.w, x1.x, x1.y, x1.z, x1.w,
                    x2.x, x2.y, x2.z, x2.w, x3.x, x3.y, x3.z, x3.w};
    #pragma unroll
    for (int i = 0; i < 16; i++){
      __bf16 h = (__bf16)xv[i];
      int row = nh * 16 + i;
      Bhi[row * 136 + k] = h;
      Blo[row * 136 + k] = (__bf16)(xv[i] - (float)h);
    }
  }
  __syncthreads();
  v4f acc[2][2];
  #pragma unroll
  for (int rt = 0; rt < 2; rt++)
    #pragma unroll
    for (int ct = 0; ct < 2; ct++) acc[rt][ct] = (v4f){0.f, 0.f, 0.f, 0.f};
  #pragma unroll
  for (int ks = 0; ks < 4; ks++){
    v8bf bhi[2], blo[2];
    #pragma unroll
    for (int ct = 0; ct < 2; ct++){
      bhi[ct] = *(const v8bf*)&Bhi[(ct * 16 + cn) * 136 + ks * 32 + qd * 8];
      blo[ct] = *(const v8bf*)&Blo[(ct * 16 + cn) * 136 + ks * 32 + qd * 8];
    }
    #pragma unroll
    for (int rt = 0; rt < 2; rt++)
      #pragma unroll
      for (int ct = 0; ct < 2; ct++){
        acc[rt][ct] = MFMA_16x16x32_BF16(ahi[rt][ks], bhi[ct], acc[rt][ct]);
        acc[rt][ct] = MFMA_16x16x32_BF16(ahi[rt][ks], blo[ct], acc[rt][ct]);
        acc[rt][ct] = MFMA_16x16x32_BF16(alo[rt][ks], bhi[ct], acc[rt][ct]);
      }
  }
  #pragma unroll
  for (int rt = 0; rt < 2; rt++){
    float bv[4];
    #pragma unroll
    for (int r = 0; r < 4; r++) bv[r] = bias[m0 + rt * 16 + qd * 4 + r] * bscale;
    #pragma unroll
    for (int ct = 0; ct < 2; ct++){
      int col = n0 + ct * 16 + cn;
      if (MODE == 1){
        v4bf kk;
        #pragma unroll
        for (int r = 0; r < 4; r++) kk[r] = (__bf16)((acc[rt][ct][r] + bv[r]) * scale);
        *(v4bf*)&Yh[(size_t)col * C_TOT + m0 + rt * 16 + qd * 4] = kk;
      } else {
        #pragma unroll
        for (int r = 0; r < 4; r++)
          Yh[(size_t)(m0 + rt * 16 + qd * 4 + r) * L_TOT + col] = (__bf16)(acc[rt][ct][r] + bv[r]);
      }
    }
  }
}

// ================= stage 1: Q projection + split-precision 2D-DCT of spatial ===========
__global__ __launch_bounds__(256) void k_q_dct(
    const float* __restrict__ freq, const float* __restrict__ spat,
    const float* __restrict__ Wq, const float* __restrict__ bq,
    __bf16* __restrict__ QT, float* __restrict__ SF){
  __shared__ __align__(16) unsigned char smraw[34560];
  int tid = threadIdx.x;
  if (blockIdx.x < 144){
    int idx = blockIdx.x;
    int b = idx / 72, n0 = (idx % 72) * 32;
    size_t off = (size_t)b * C_TOT * L_TOT;
    mfma_proj<1>(Wq, bq, freq + off, QT + (size_t)b * L_TOT * C_TOT, 1.0f, 1.0f, n0, (__bf16*)smraw, tid);
    return;
  }
  int img = blockIdx.x - 144;            // 0..255 : b*128 + c
  __bf16* Xhi = (__bf16*)smraw;          // [48][72] each, cols 48..63 zero-padded
  __bf16* Xlo = Xhi + 3456;
  __bf16* Dm  = Xhi + 6912;              // D[a][n]
  __bf16* Thi = Xhi + 10368;             // T^T[w][m]
  __bf16* Tlo = Xhi + 13824;
  const float* src = spat + (size_t)img * 2304;
  for (int i = tid; i < 8640; i += 256) ((unsigned int*)smraw)[i] = 0u;
  __syncthreads();
  for (int i = tid; i < 2304; i += 256){
    int a = i / 48, n = i - a * 48;
    int m = ((2 * n + 1) * a) % 192;      // exact angle reduction, cos period = 192
    float v = cosf(0.032724923474893679f * (float)m) * 0.204124145231931508f;
    if (a == 0) v *= 0.707106781186547524f;
    Dm[a * 72 + n] = (__bf16)v;
  }
  for (int i = tid; i < 2304; i += 256){
    int mm = i / 48, n = i - mm * 48;
    float v = src[i];
    __bf16 h = (__bf16)v;
    Xhi[mm * 72 + n] = h;
    Xlo[mm * 72 + n] = (__bf16)(v - (float)h);
  }
  __syncthreads();
  int wave = tid >> 6, lane = tid & 63, qd = lane >> 4, cn = lane & 15;
  // pass 1: T[m][w] = sum_n X[m][n] D[w][n]
  for (int t = wave; t < 9; t += 4){
    int mi = t / 3, wi = t - mi * 3;
    v8bf ah0 = *(const v8bf*)&Xhi[(mi * 16 + cn) * 72 + qd * 8];
    v8bf ah1 = *(const v8bf*)&Xhi[(mi * 16 + cn) * 72 + 32 + qd * 8];
    v8bf al0 = *(const v8bf*)&Xlo[(mi * 16 + cn) * 72 + qd * 8];
    v8bf al1 = *(const v8bf*)&Xlo[(mi * 16 + cn) * 72 + 32 + qd * 8];
    v8bf b0 = *(const v8bf*)&Dm[(wi * 16 + cn) * 72 + qd * 8];
    v8bf b1 = *(const v8bf*)&Dm[(wi * 16 + cn) * 72 + 32 + qd * 8];
    v4f acc = (v4f){0.f, 0.f, 0.f, 0.f};
    acc = MFMA_16x16x32_BF16(ah0, b0, acc);
    acc = MFMA_16x16x32_BF16(ah1, b1, acc);
    acc = MFMA_16x16x32_BF16(al0, b0, acc);
    acc = MFMA_16x16x32_BF16(al1, b1, acc);
    v4bf th, tl;
    #pragma unroll
    for (int r = 0; r < 4; r++){
      __bf16 h = (__bf16)acc[r];
      th[r] = h;
      tl[r] = (__bf16)(acc[r] - (float)h);
    }
    *(v4bf*)&Thi[(wi * 16 + cn) * 72 + mi * 16 + qd * 4] = th;
    *(v4bf*)&Tlo[(wi * 16 + cn) * 72 + mi * 16 + qd * 4] = tl;
  }
  __syncthreads();
  // pass 2: F[h][w] = sum_m D[h][m] T[m][w]
  float* dst = SF + (size_t)img * 2304;
  for (int t = wave; t < 9; t += 4){
    int hi_ = t / 3, wi = t - hi_ * 3;
    v8bf a0 = *(const v8bf*)&Dm[(hi_ * 16 + cn) * 72 + qd * 8];
    v8bf a1 = *(const v8bf*)&Dm[(hi_ * 16 + cn) * 72 + 32 + qd * 8];
    v8bf bh0 = *(const v8bf*)&Thi[(wi * 16 + cn) * 72 + qd * 8];
    v8bf bh1 = *(const v8bf*)&Thi[(wi * 16 + cn) * 72 + 32 + qd * 8];
    v8bf bl0 = *(const v8bf*)&Tlo[(wi * 16 + cn) * 72 + qd * 8];
    v8bf bl1 = *(const v8bf*)&Tlo[(wi * 16 + cn) * 72 + 32 + qd * 8];
    v4f acc = (v4f){0.f, 0.f, 0.f, 0.f};
    acc = MFMA_16x16x32_BF16(a0, bh0, acc);
    acc = MFMA_16x16x32_BF16(a1, bh1, acc);
    acc = MFMA_16x16x32_BF16(a0, bl0, acc);
    acc = MFMA_16x16x32_BF16(a1, bl1, acc);
    int w = wi * 16 + cn;
    #pragma unroll
    for (int r = 0; r < 4; r++)
      dst[(size_t)(hi_ * 16 + qd * 4 + r) * 48 + w] = acc[r];
  }
}

// ================= stage 2: K,V projections from DCT'd spatial =================
__global__ __launch_bounds__(256) void k_kv(
    const float* __restrict__ SF,
    const float* __restrict__ Wk, const float* __restrict__ bk,
    const float* __restrict__ Wv, const float* __restrict__ bv,
    __bf16* __restrict__ KT, __bf16* __restrict__ Vg){
  __shared__ __align__(16) unsigned char smraw[17408];
  int job = blockIdx.x / 144;
  int idx = blockIdx.x % 144;
  int b = idx / 72, n0 = (idx % 72) * 32;
  size_t off = (size_t)b * C_TOT * L_TOT;
  if (job == 0)
    mfma_proj<1>(Wk, bk, SF + off, KT + (size_t)b * L_TOT * C_TOT, KSCALE, 1.0f, n0, (__bf16*)smraw, threadIdx.x);
  else
    mfma_proj<2>(Wv, bv, SF + off, Vg + off, 1.0f, 1.0f, n0, (__bf16*)smraw, threadIdx.x);
}

// ================= stage 3: 8-wave flash attention, V in registers =================
// 512 threads; per 256-key chunk, wave w owns keys w*32..w*32+31 with a PRIVATE
// double-buffered K slice in LDS (global_load_lds) and V loaded straight into a
// register (the PV A-fragment IS the 16B the lane loads). Counted vmcnt(2), no
// __syncthreads in the main loop. 3 blocks/CU x 8 waves = 24 waves/CU.
__device__ __forceinline__ void attn_step(
    int ch, int prefetch, __bf16* KtW, const __bf16* KTb, const __bf16* Vb,
    int c0, int wave, int lane, int qd, int cn,
    const v8bf (&qf)[3], const v8bf& vUse, v8bf& vNext,
    v4f (&acc)[3], float (&den)[3]){
  if (prefetch){
    int s0n = (ch + 1) * 256 + wave * 32;
    async_cp16(KTb + (size_t)(s0n + (lane >> 1)) * C_TOT + c0 + (lane & 1) * 8,
               KtW + (((ch + 1) & 1) << 9) + lane * 8);
    vNext = *(const v8bf*)(Vb + (size_t)cn * L_TOT + (ch + 1) * 256 + wave * 32 + qd * 8);
    asm volatile("s_waitcnt vmcnt(2)" ::: "memory");   // chunk ch's K+V landed
  } else {
    asm volatile("s_waitcnt vmcnt(0)" ::: "memory");
  }
  __builtin_amdgcn_sched_barrier(0);                   // no hoisting past the wait
  const __bf16* Kt = KtW + ((ch & 1) << 9);
  v8bf a0, a1;
  #pragma unroll
  for (int j = 0; j < 8; j++){ a0[j] = (__bf16)0.0f; a1[j] = (__bf16)0.0f; }
  if (qd < 2){
    a0 = *(const v8bf*)&Kt[cn * 16 + qd * 8];
    a1 = *(const v8bf*)&Kt[(16 + cn) * 16 + qd * 8];
  }
  #pragma unroll
  for (int t = 0; t < 3; t++){
    v4f z = {0.f, 0.f, 0.f, 0.f};
    v4f st0 = MFMA_16x16x32_BF16(a0, qf[t], z);
    v4f st1 = MFMA_16x16x32_BF16(a1, qf[t], z);
    float p0[4], p1[4];
    #pragma unroll
    for (int i = 0; i < 4; i++){
      p0[i] = EXP2(st0[i]); den[t] += p0[i];
      p1[i] = EXP2(st1[i]); den[t] += p1[i];
    }
    v4bf cc0, cc1;
    #pragma unroll
    for (int i = 0; i < 4; i++){ cc0[i] = (__bf16)p0[i]; cc1[i] = (__bf16)p1[i]; }
    unsigned U0 = ((unsigned*)&cc0)[0], U1 = ((unsigned*)&cc0)[1];
    unsigned U2 = ((unsigned*)&cc1)[0], U3 = ((unsigned*)&cc1)[1];
    pl32swap(U0, U2); pl32swap(U1, U3);
    pl16swap(U0, U2); pl16swap(U1, U3);
    v8bf pf;
    ((unsigned*)&pf)[0] = U0; ((unsigned*)&pf)[1] = U1;
    ((unsigned*)&pf)[2] = U2; ((unsigned*)&pf)[3] = U3;
    acc[t] = MFMA_16x16x32_BF16(vUse, pf, acc[t]);
  }
}

__global__ __launch_bounds__(512) void k_attn(const __bf16* __restrict__ QT,
                                              const __bf16* __restrict__ KT,
                                              const __bf16* __restrict__ V,
                                              __bf16* __restrict__ AO){
  const int L = L_TOT;
  int bh = blockIdx.y;
  int b = bh >> 3, h = bh & 7;
  int c0 = h * 16;
  const __bf16* QTb = QT + (size_t)b * L * C_TOT;
  const __bf16* KTb = KT + (size_t)b * L * C_TOT;
  const __bf16* Vb  = V  + ((size_t)b * C_TOT + c0) * L;
  int tid = threadIdx.x;
  int wave = tid >> 6, lane = tid & 63;
  int qd = lane >> 4, cn = lane & 15;
  int l0 = blockIdx.x * 48;

  // per-wave private K: [8 waves][2 bufs][32 keys][16 ch] = 16 KB total
  __shared__ __align__(16) __bf16 smem[8192];
  __bf16* KtW = smem + wave * 1024;

  v8bf qf[3];
  #pragma unroll
  for (int t = 0; t < 3; t++){
    #pragma unroll
    for (int j = 0; j < 8; j++) qf[t][j] = (__bf16)0.0f;
  }
  if (qd < 2){
    #pragma unroll
    for (int t = 0; t < 3; t++)
      qf[t] = *(const v8bf*)&QTb[(size_t)(l0 + t * 16 + cn) * C_TOT + c0 + qd * 8];
  }

  v4f acc[3];
  float den[3] = {0.f, 0.f, 0.f};
  #pragma unroll
  for (int t = 0; t < 3; t++) acc[t] = (v4f){0.f, 0.f, 0.f, 0.f};

  v8bf vA, vB;
  // prologue: chunk 0 -> K buf 0 + vA
  async_cp16(KTb + (size_t)(wave * 32 + (lane >> 1)) * C_TOT + c0 + (lane & 1) * 8,
             KtW + lane * 8);
  vA = *(const v8bf*)(Vb + (size_t)cn * L + wave * 32 + qd * 8);

  for (int cc = 0; cc < 4; cc++){
    attn_step(2 * cc,     1, KtW, KTb, Vb, c0, wave, lane, qd, cn, qf, vA, vB, acc, den);
    attn_step(2 * cc + 1, 1, KtW, KTb, Vb, c0, wave, lane, qd, cn, qf, vB, vA, acc, den);
  }
  attn_step(8, 0, KtW, KTb, Vb, c0, wave, lane, qd, cn, qf, vA, vB, acc, den);

  // ---- cross-wave combine: 8 -> 4 waves, then 12-slot scheme (15 KB in smem) ----
  __syncthreads();
  float* redA = (float*)smem;            // 3072 floats
  float* redD = (float*)smem + 3072;     // 768 floats
  if (wave >= 4){
    #pragma unroll
    for (int t = 0; t < 3; t++){
      *(v4f*)&redA[(((wave - 4) * 3 + t) * 64 + lane) * 4] = acc[t];
      redD[((wave - 4) * 3 + t) * 64 + lane] = den[t];
    }
  }
  __syncthreads();
  if (wave < 4){
    #pragma unroll
    for (int t = 0; t < 3; t++){
      v4f xx = *(const v4f*)&redA[((wave * 3 + t) * 64 + lane) * 4];
      acc[t][0] += xx[0]; acc[t][1] += xx[1]; acc[t][2] += xx[2]; acc[t][3] += xx[3];
      den[t] += redD[(wave * 3 + t) * 64 + lane];
    }
  }
  __syncthreads();
  if (wave < 4){
    #pragma unroll
    for (int t = 0; t < 3; t++){
      *(v4f*)&redA[((wave * 3 + t) * 64 + lane) * 4] = acc[t];
      redD[(wave * 3 + t) * 64 + lane] = den[t];
    }
  }
  __syncthreads();
  if (wave < 3){
    int t = wave;
    v4f a = (v4f){0.f, 0.f, 0.f, 0.f};
    float dn = 0.f;
    #pragma unroll
    for (int w2 = 0; w2 < 4; w2++){
      v4f xx = *(const v4f*)&redA[((w2 * 3 + t) * 64 + lane) * 4];
      a[0] += xx[0]; a[1] += xx[1]; a[2] += xx[2]; a[3] += xx[3];
      dn += redD[(w2 * 3 + t) * 64 + lane];
    }
    dn += __shfl_xor(dn, 16);
    dn += __shfl_xor(dn, 32);
    float inv = 1.0f / dn;
    __bf16* Ao = AO + ((size_t)b * C_TOT + c0) * L;
    #pragma unroll
    for (int r2 = 0; r2 < 4; r2++)
      Ao[(size_t)(qd * 4 + r2) * L + l0 + t * 16 + cn] = (__bf16)(a[r2] * inv);
  }
}

// ================= output projection (bf16 B, W split in regs) =================
__global__ __launch_bounds__(256) void k_oproj(const __bf16* __restrict__ AO,
                                               const float* __restrict__ Wo, const float* __restrict__ bo,
                                               float* __restrict__ out){
  __shared__ __align__(16) __bf16 Bs[32 * 136];
  int b = blockIdx.y, n0 = blockIdx.x * 32;
  int tid = threadIdx.x;
  const int wave = tid >> 6, lane = tid & 63, qd = lane >> 4, cn = lane & 15;
  const int m0 = wave * 32;
  v8bf ahi[2][4], alo[2][4];
  #pragma unroll
  for (int rt = 0; rt < 2; rt++)
    #pragma unroll
    for (int ks = 0; ks < 4; ks++){
      const float* wp = Wo + (size_t)(m0 + rt * 16 + cn) * C_TOT + ks * 32 + qd * 8;
      float4 w0 = *(const float4*)wp;
      float4 w1 = *(const float4*)(wp + 4);
      float wv[8] = {w0.x, w0.y, w0.z, w0.w, w1.x, w1.y, w1.z, w1.w};
      #pragma unroll
      for (int j = 0; j < 8; j++){
        __bf16 h = (__bf16)wv[j];
        ahi[rt][ks][j] = h;
        alo[rt][ks][j] = (__bf16)(wv[j] - (float)h);
      }
    }
  {
    int k = tid >> 1, nh = tid & 1;
    const __bf16* src = AO + ((size_t)b * C_TOT + k) * L_TOT + n0 + nh * 16;
    v8bf x0 = *(const v8bf*)src;
    v8bf x1 = *(const v8bf*)(src + 8);
    #pragma unroll
    for (int i = 0; i < 8; i++){
      Bs[(nh * 16 + i) * 136 + k] = x0[i];
      Bs[(nh * 16 + 8 + i) * 136 + k] = x1[i];
    }
  }
  __syncthreads();
  v4f acc[2][2];
  #pragma unroll
  for (int rt = 0; rt < 2; rt++)
    #pragma unroll
    for (int ct = 0; ct < 2; ct++) acc[rt][ct] = (v4f){0.f, 0.f, 0.f, 0.f};
  #pragma unroll
  for (int ks = 0; ks < 4; ks++){
    v8bf bf[2];
    #pragma unroll
    for (int ct = 0; ct < 2; ct++)
      bf[ct] = *(const v8bf*)&Bs[(ct * 16 + cn) * 136 + ks * 32 + qd * 8];
    #pragma unroll
    for (int rt = 0; rt < 2; rt++)
      #pragma unroll
      for (int ct = 0; ct < 2; ct++){
        acc[rt][ct] = MFMA_16x16x32_BF16(ahi[rt][ks], bf[ct], acc[rt][ct]);
        acc[rt][ct] = MFMA_16x16x32_BF16(alo[rt][ks], bf[ct], acc[rt][ct]);
      }
  }
  float* ob = out + (size_t)b * C_TOT * L_TOT;
  #pragma unroll
  for (int rt = 0; rt < 2; rt++){
    float bv[4];
    #pragma unroll
    for (int r = 0; r < 4; r++) bv[r] = bo[m0 + rt * 16 + qd * 4 + r];
    #pragma unroll
    for (int ct = 0; ct < 2; ct++){
      int col = n0 + ct * 16 + cn;
      #pragma unroll
      for (int r = 0; r < 4; r++)
        ob[(size_t)(m0 + rt * 16 + qd * 4 + r) * L_TOT + col] = acc[rt][ct][r] + bv[r];
    }
  }
}

extern "C" void kernel_launch(void* const* d_in, const int* in_sizes, int n_in,
                              void* d_out, int out_size, void* d_ws, size_t ws_size,
                              hipStream_t stream){
  const float* freq = (const float*)d_in[0];
  const float* spat = (const float*)d_in[1];
  const float* Wq = (const float*)d_in[2]; const float* bq = (const float*)d_in[3];
  const float* Wk = (const float*)d_in[4]; const float* bk = (const float*)d_in[5];
  const float* Wv = (const float*)d_in[6]; const float* bv = (const float*)d_in[7];
  const float* Wo = (const float*)d_in[8]; const float* bo = (const float*)d_in[9];
  __bf16* base = (__bf16*)d_ws;

  __bf16* QTg = base;                       // [b][l][c]
  __bf16* KTg = base + 589824;              // [b][l][c], +bk, *KSCALE
  __bf16* Vg  = base + 1179648;             // [b][c][l], +bv
  __bf16* AOg = base + 1769472;             // [b][c][l]
  float*  SFg = (float*)(base + 2359296);   // [b][c][l] fp32, DCT'd spatial
  float* out = (float*)d_out;

  k_q_dct<<<dim3(400), dim3(256), 0, stream>>>(freq, spat, Wq, bq, QTg, SFg);
  k_kv<<<dim3(288), dim3(256), 0, stream>>>(SFg, Wk, bk, Wv, bv, KTg, Vg);
  k_attn<<<dim3(48, 16), dim3(512), 0, stream>>>(QTg, KTg, Vg, AOg);
  k_oproj<<<dim3(72, 2), dim3(256), 0, stream>>>(AOg, Wo, bo, out);
}